// Round 1
// baseline (3000.243 us; speedup 1.0000x reference)
//
#include <hip/hip_runtime.h>
#include <math.h>

#define SEQ    1024
#define EMBED  300
#define HIDDEN 512
#define G4     2048          // 4*HIDDEN, gate order i,f,g,o
#define NB     32            // persistent blocks in phase 2
#define UPB    (HIDDEN/NB)   // hidden units owned per block = 16
#define PAD_IDX 1

// ---- device-global scratch (avoids ws_size uncertainty; fully rewritten
// every launch: counter zeroed + hbuf re-inited by xgates_kernel, xg fully
// overwritten, so every call does identical work) ----
__device__ float        g_xg[SEQ * G4];     // x @ W_ih^T + b_ih + b_hh
__device__ float        g_hbuf[2 * HIDDEN]; // ping-pong h broadcast buffer
__device__ unsigned int g_counter;          // grid barrier counter

__device__ __forceinline__ float sigmoidf_(float x) {
    return 1.f / (1.f + __expf(-x));
}

// ---------------------------------------------------------------------------
// Phase 1: xg[t][k] = dot(emb[token[t]], W_ih[k]) + b_ih[k] + b_hh[k]
// grid = 256 blocks (128 t-tiles of 8 tokens x 2 k-halves), 256 threads.
// Block 0 additionally zeroes the barrier counter and seeds hbuf[0] = h0.
// ---------------------------------------------------------------------------
__global__ __launch_bounds__(256) void xgates_kernel(
    const int* __restrict__ seq, const float* __restrict__ h0,
    const float* __restrict__ emb, const float* __restrict__ W_ih,
    const float* __restrict__ b_ih, const float* __restrict__ b_hh)
{
    const int bx = blockIdx.x, tid = threadIdx.x;
    if (bx == 0) {
        if (tid == 0) g_counter = 0u;
        for (int i = tid; i < HIDDEN; i += 256) g_hbuf[i] = h0[i];
        // (kernel-boundary flush makes these visible to phase 2)
    }
    const int t_tile = bx >> 1, k_half = bx & 1;
    const int t0 = t_tile * 8;

    __shared__ int tok_s[8];
    __shared__ __align__(16) float embt[8][304]; // 304: pad, keeps float4 alignment

    if (tid < 8) tok_s[tid] = seq[t0 + tid];
    __syncthreads();
    for (int idx = tid; idx < 8 * EMBED; idx += 256) {
        int tt = idx / EMBED;
        int e  = idx - tt * EMBED;
        embt[tt][e] = emb[(size_t)tok_s[tt] * EMBED + e];
    }
    __syncthreads();

    const int kbase = k_half * 1024 + tid;
    const float4* wr0 = (const float4*)(W_ih + (size_t)(kbase      ) * EMBED);
    const float4* wr1 = (const float4*)(W_ih + (size_t)(kbase + 256) * EMBED);
    const float4* wr2 = (const float4*)(W_ih + (size_t)(kbase + 512) * EMBED);
    const float4* wr3 = (const float4*)(W_ih + (size_t)(kbase + 768) * EMBED);

    float acc[4][8];
    #pragma unroll
    for (int kk = 0; kk < 4; kk++)
        #pragma unroll
        for (int tt = 0; tt < 8; tt++) acc[kk][tt] = 0.f;

    for (int e4 = 0; e4 < EMBED / 4; e4++) {  // 75 iters
        float4 em[8];
        #pragma unroll
        for (int tt = 0; tt < 8; tt++)
            em[tt] = *(const float4*)&embt[tt][e4 * 4];
        float4 w[4];
        w[0] = wr0[e4]; w[1] = wr1[e4]; w[2] = wr2[e4]; w[3] = wr3[e4];
        #pragma unroll
        for (int kk = 0; kk < 4; kk++) {
            #pragma unroll
            for (int tt = 0; tt < 8; tt++) {
                float a = acc[kk][tt];
                a = fmaf(w[kk].x, em[tt].x, a);
                a = fmaf(w[kk].y, em[tt].y, a);
                a = fmaf(w[kk].z, em[tt].z, a);
                a = fmaf(w[kk].w, em[tt].w, a);
                acc[kk][tt] = a;
            }
        }
    }
    #pragma unroll
    for (int kk = 0; kk < 4; kk++) {
        int k = kbase + kk * 256;
        float bias = b_ih[k] + b_hh[k];
        #pragma unroll
        for (int tt = 0; tt < 8; tt++)
            g_xg[(size_t)(t0 + tt) * G4 + k] = acc[kk][tt] + bias;
    }
}

// ---------------------------------------------------------------------------
// Phase 2: persistent cooperative LSTM recurrence.
// 32 blocks x 256 threads. W_hh lives in registers (128 floats/thread).
// Thread (w = tid/4, c = tid%4): row w of the block's 64 rows
// (w = gate*16 + unit), chunk c covers h[c*128 .. c*128+128) rotated by 4c
// elements so the 4 distinct ds_read_b128 broadcast addresses per wave hit
// disjoint bank groups.
// ---------------------------------------------------------------------------
__global__ __launch_bounds__(256) void lstm_kernel(
    const int* __restrict__ seq, const float* __restrict__ h0,
    const float* __restrict__ c0, const float* __restrict__ Whh,
    float* __restrict__ out)
{
    const int b = blockIdx.x, tid = threadIdx.x;
    const int w = tid >> 2, c = tid & 3;
    const int g = w >> 4, uu = w & 15;
    const int R = g * HIDDEN + b * UPB + uu;

    const float* wrow = Whh + (size_t)R * HIDDEN + c * 128;
    float4 wreg[32];
    #pragma unroll
    for (int i = 0; i < 32; i++) {
        int off = (4 * i + 4 * c) & 127;   // rotated traversal
        wreg[i] = *(const float4*)(wrow + off);
    }

    __shared__ __align__(16) float h_lds[HIDDEN];
    __shared__ float gate_lds[64];

    float c_state = 0.f, h_state = 0.f;
    if (tid < UPB) {
        c_state = c0[b * UPB + tid];
        h_state = h0[b * UPB + tid];
    }

    int p = 0;               // current h buffer parity
    unsigned nonpad = 0;
    bool any = false;

    for (int t = 0; t < SEQ; t++) {
        int tok = seq[t];                 // uniform scalar load
        if (tok == PAD_IDX) continue;     // uniform across grid: skip step+barrier
        any = true;

        // prefetch this step's input-gate contributions (independent of h)
        float xi = 0.f, xf = 0.f, xgg = 0.f, xo = 0.f;
        if (tid < UPB) {
            const float* xr = g_xg + (size_t)t * G4 + b * UPB + tid;
            xi  = xr[0];
            xf  = xr[HIDDEN];
            xgg = xr[2 * HIDDEN];
            xo  = xr[3 * HIDDEN];
        }

        // stage h (agent-scope relaxed atomic loads -> always coherent)
        {
            const float* hb = g_hbuf + p * HIDDEN;
            float v0 = __hip_atomic_load(hb + 2 * tid,     __ATOMIC_RELAXED, __HIP_MEMORY_SCOPE_AGENT);
            float v1 = __hip_atomic_load(hb + 2 * tid + 1, __ATOMIC_RELAXED, __HIP_MEMORY_SCOPE_AGENT);
            h_lds[2 * tid]     = v0;
            h_lds[2 * tid + 1] = v1;
        }
        __syncthreads();

        // 128-length partial dot from registers x LDS broadcasts
        const float* hc = h_lds + c * 128;
        float4 a4 = {0.f, 0.f, 0.f, 0.f};
        #pragma unroll
        for (int i = 0; i < 32; i++) {
            int off = (4 * i + 4 * c) & 127;
            float4 h4 = *(const float4*)(hc + off);
            a4.x = fmaf(wreg[i].x, h4.x, a4.x);
            a4.y = fmaf(wreg[i].y, h4.y, a4.y);
            a4.z = fmaf(wreg[i].z, h4.z, a4.z);
            a4.w = fmaf(wreg[i].w, h4.w, a4.w);
        }
        float dot = (a4.x + a4.y) + (a4.z + a4.w);
        dot += __shfl_xor(dot, 1);
        dot += __shfl_xor(dot, 2);
        if (c == 0) gate_lds[w] = dot;
        __syncthreads();

        // gate combine: 16 owner threads, state stays in registers
        if (tid < UPB) {
            float iv = sigmoidf_(xi  + gate_lds[tid]);
            float fv = sigmoidf_(xf  + gate_lds[16 + tid]);
            float gv = tanhf    (xgg + gate_lds[32 + tid]);
            float ov = sigmoidf_(xo  + gate_lds[48 + tid]);
            c_state = fv * c_state + iv * gv;
            h_state = ov * tanhf(c_state);
            // publish straight to the coherence point
            __hip_atomic_store(g_hbuf + (p ^ 1) * HIDDEN + b * UPB + tid, h_state,
                               __ATOMIC_RELAXED, __HIP_MEMORY_SCOPE_AGENT);
        }
        p ^= 1;
        nonpad++;

        __syncthreads();   // all stores issued & drained before arrival
        if (tid == 0) {
            __hip_atomic_fetch_add(&g_counter, 1u, __ATOMIC_ACQ_REL, __HIP_MEMORY_SCOPE_AGENT);
            unsigned target = nonpad * NB;
            while (__hip_atomic_load(&g_counter, __ATOMIC_ACQUIRE, __HIP_MEMORY_SCOPE_AGENT) < target) {
                __builtin_amdgcn_s_sleep(1);
            }
        }
        __syncthreads();
    }

    if (tid < UPB) {
        int u = b * UPB + tid;
        out[u]              = any ? h_state : 0.f;  // out (last non-pad h_new, else 0)
        out[HIDDEN + u]     = h_state;              // h_final
        out[2 * HIDDEN + u] = c_state;              // c_final
    }
}

// ---------------------------------------------------------------------------
extern "C" void kernel_launch(void* const* d_in, const int* in_sizes, int n_in,
                              void* d_out, int out_size, void* d_ws, size_t ws_size,
                              hipStream_t stream)
{
    const int*   seq  = (const int*)  d_in[0];
    const float* h0   = (const float*)d_in[1];
    const float* c0   = (const float*)d_in[2];
    const float* emb  = (const float*)d_in[3];
    const float* W_ih = (const float*)d_in[4];
    const float* W_hh = (const float*)d_in[5];
    const float* b_ih = (const float*)d_in[6];
    const float* b_hh = (const float*)d_in[7];
    float* out = (float*)d_out;

    hipLaunchKernelGGL(xgates_kernel, dim3(256), dim3(256), 0, stream,
                       seq, h0, emb, W_ih, b_ih, b_hh);

    void* args[] = { (void*)&seq, (void*)&h0, (void*)&c0, (void*)&W_hh, (void*)&out };
    hipLaunchCooperativeKernel((const void*)lstm_kernel, dim3(NB), dim3(256),
                               args, 0, stream);
}